// Round 4
// baseline (875.125 us; speedup 1.0000x reference)
//
#include <hip/hip_runtime.h>
#include <math.h>

#define INV3 0.57735026918962576f       // 1/sqrt(3)
#define RS8  0.35355339059327373f       // 1/sqrt(8)
#define RS32 0.17677669529663687f       // 1/sqrt(32)
#define RS64 0.125f                     // 1/sqrt(64)
#define RS96 0.10206207261596575f       // 1/sqrt(96)
#define CAP  64                          // max in-degree (Poisson(16): P(>64) ~ 1e-20)

typedef _Float16 v8h   __attribute__((ext_vector_type(8)));
typedef float    f32x4 __attribute__((ext_vector_type(4)));

// swizzled-weight arena offsets (in f16 elements)
#define OFF_W2    0        // fc_w2   64x192, *RS64       : 2ks x 12nt
#define OFF_L2W0  12288    // lin2_w0 96x64,  *RS96*rs    : 3ks x 4nt
#define OFF_L2W1  18432    // lin2_w1 96x32,  *RS96*rs    : 3ks x 2nt
#define OFF_SCW0  21504    // sc_w0   64x64,  *RS64       : 2ks x 4nt
#define OFF_SCW1  25600    // sc_w1   32x32,  *RS32       : 1ks x 2nt
#define OFF_L1W0  26624    // lin1_w0 64x64,  *RS64       : 2ks x 4nt
#define OFF_L1W1  30720    // lin1_w1 32x32,  *RS32       : 1ks x 2nt
#define SWZ_TOTAL 31744

#define MFMA16(a,b,c) __builtin_amdgcn_mfma_f32_16x16x32_f16((a),(b),(c),0,0,0)

// ---------------------------------------------------------------------------
// Swizzle all weight matrices into MFMA B-fragment f16 arena.
// B-frag (16x16x32): frag (ks,nt) elem lane*8+j = W[ks*32+(l>>4)*8+j][nt*16+(l&15)]*s
// frag order within a matrix: ks-major, nt-minor: (ks*NT+nt)*512.
// ---------------------------------------------------------------------------
__global__ void swizzle_all(const float* __restrict__ fc_w2,
                            const float* __restrict__ lin2_w0,
                            const float* __restrict__ lin2_w1,
                            const float* __restrict__ sc_w0,
                            const float* __restrict__ sc_w1,
                            const float* __restrict__ lin1_w0,
                            const float* __restrict__ lin1_w1,
                            const int* __restrict__ nn,
                            _Float16* __restrict__ B) {
    int idx = blockIdx.x * blockDim.x + threadIdx.x;
    if (idx >= SWZ_TOTAL) return;
    float rs = rsqrtf((float)nn[0]);
    const float* W; int M, off; float s;
    if      (idx < OFF_L2W0) { W = fc_w2;   M = 192; off = OFF_W2;   s = RS64; }
    else if (idx < OFF_L2W1) { W = lin2_w0; M = 64;  off = OFF_L2W0; s = RS96 * rs; }
    else if (idx < OFF_SCW0) { W = lin2_w1; M = 32;  off = OFF_L2W1; s = RS96 * rs; }
    else if (idx < OFF_SCW1) { W = sc_w0;   M = 64;  off = OFF_SCW0; s = RS64; }
    else if (idx < OFF_L1W0) { W = sc_w1;   M = 32;  off = OFF_SCW1; s = RS32; }
    else if (idx < OFF_L1W1) { W = lin1_w0; M = 64;  off = OFF_L1W0; s = RS64; }
    else                     { W = lin1_w1; M = 32;  off = OFF_L1W1; s = RS32; }
    int rel  = idx - off;
    int j    = rel & 7, l = (rel >> 3) & 63, frag = rel >> 9;
    int NT   = M >> 4;
    int nt   = frag % NT, ks = frag / NT;
    int k    = ks * 32 + ((l >> 4) << 3) + j;
    int n    = (nt << 4) + (l & 15);
    B[idx] = (_Float16)(W[k * M + n] * s);
}

// ---------------------------------------------------------------------------
// CSR build
// ---------------------------------------------------------------------------
__global__ void fill_csr(const int* __restrict__ edge_dst, int* __restrict__ deg,
                         int* __restrict__ bucket, int E) {
    int e = blockIdx.x * blockDim.x + threadIdx.x;
    if (e >= E) return;
    int d = edge_dst[e];
    int pos = atomicAdd(&deg[d], 1);
    if (pos < CAP) bucket[(size_t)d * CAP + pos] = e;
}

// ---------------------------------------------------------------------------
// Prep: f = lin1-fctp(node_input) via MFMA, 16 nodes per single-wave block.
// ---------------------------------------------------------------------------
__global__ __launch_bounds__(64) void prep_mfma(
    const float* __restrict__ ni, const float* __restrict__ na,
    const _Float16* __restrict__ Bsw, float* __restrict__ fout, int N)
{
    __shared__ __align__(16) _Float16 Xs[16][72];
    __shared__ __align__(16) _Float16 Xv[3][16][40];
    __shared__ float At[16];
    const int lane = threadIdx.x;
    const int n0 = blockIdx.x * 16;
    // de-interleave staging: j -> Xs (j<64) or Xv[d][.][u], d=(j-64)%3, u=(j-64)/3
    const int j1 = lane + 64, j2 = lane + 128;
    _Float16* xd1 = &Xv[(j1 - 64) % 3][0][(j1 - 64) / 3];
    _Float16* xd2 = (lane < 32) ? &Xv[(j2 - 64) % 3][0][(j2 - 64) / 3] : (_Float16*)0;
    for (int m = 0; m < 16; ++m) {
        const float* row = ni + (size_t)min(n0 + m, N - 1) * 160;
        Xs[m][lane] = (_Float16)row[lane];
        xd1[m * 40] = (_Float16)row[j1];
        if (lane < 32) xd2[m * 40] = (_Float16)row[j2];
    }
    if (lane < 16) At[lane] = na[min(n0 + lane, N - 1)];
    __syncthreads();

    const int m16 = lane & 15, quad = lane >> 4;
    v8h A0 = *(const v8h*)&Xs[m16][quad * 8];
    v8h A1 = *(const v8h*)&Xs[m16][32 + quad * 8];
    const _Float16* B0 = Bsw + OFF_L1W0;
    #pragma unroll
    for (int nt = 0; nt < 4; ++nt) {
        f32x4 c = {0.f, 0.f, 0.f, 0.f};
        c = MFMA16(A0, *(const v8h*)&B0[(0 * 4 + nt) * 512 + lane * 8], c);
        c = MFMA16(A1, *(const v8h*)&B0[(1 * 4 + nt) * 512 + lane * 8], c);
        #pragma unroll
        for (int r = 0; r < 4; ++r) {
            int rr = quad * 4 + r, n = n0 + rr;
            if (n < N) fout[(size_t)n * 160 + nt * 16 + m16] = c[r] * At[rr];
        }
    }
    const _Float16* B1 = Bsw + OFF_L1W1;
    #pragma unroll
    for (int d = 0; d < 3; ++d) {
        v8h Ad = *(const v8h*)&Xv[d][m16][quad * 8];
        #pragma unroll
        for (int nt = 0; nt < 2; ++nt) {
            f32x4 c = {0.f, 0.f, 0.f, 0.f};
            c = MFMA16(Ad, *(const v8h*)&B1[nt * 512 + lane * 8], c);
            #pragma unroll
            for (int r = 0; r < 4; ++r) {
                int rr = quad * 4 + r, n = n0 + rr;
                if (n < N) fout[(size_t)n * 160 + 64 + (nt * 16 + m16) * 3 + d] = c[r] * At[rr];
            }
        }
    }
}

// ---------------------------------------------------------------------------
// Aggregation: one node per single-wave block. Per 16-edge chunk:
// meta -> issue ALL f-gathers (regs) -> H -> W via MFMA (overlaps gathers)
// -> TP (branch-free, zero-padded). Writes mid as f16.
// ---------------------------------------------------------------------------
__global__ __launch_bounds__(64, 4) void node_main(
    const float* __restrict__ edge_attr,     // E x 4
    const float* __restrict__ edge_scalars,  // E x 8
    const float* __restrict__ fc_w1,         // 8 x 64
    const float* __restrict__ f,             // N x 160
    const _Float16* __restrict__ Bsw,        // swizzled arena
    const int* __restrict__ deg,
    const int* __restrict__ bucket,
    const int* __restrict__ edge_src,
    _Float16* __restrict__ mid16,            // N x 384
    int N)
{
    __shared__ __align__(16) _Float16 Hl[1024];      // 16 edges x 64 k
    __shared__ __align__(16) _Float16 Wl[16 * 208];
    __shared__ __align__(16) float    ES[16][8];
    __shared__ __align__(16) float    EA[16][4];
    __shared__ int SRC[16];

    const int lane = threadIdx.x;
    const int n    = blockIdx.x;
    if (n >= N) return;

    float fw1[8];
    #pragma unroll
    for (int u = 0; u < 8; ++u) fw1[u] = fc_w1[u * 64 + lane];

    int deg_n = min(deg[n], CAP);
    int nch = (deg_n + 15) >> 4;

    float a0 = 0.f, a1x = 0.f, a1y = 0.f, a1z = 0.f;
    float a2x = 0.f, a2y = 0.f, a2z = 0.f;
    const int m16  = lane & 15;
    const int quad = lane >> 4;
    const int wv   = lane & 31;
    const int wv3  = 64 + wv * 3;
    const _Float16* Bw2 = Bsw + OFF_W2;

    for (int ch = 0; ch < nch; ++ch) {
        int vcnt = deg_n - ch * 16;
        vcnt = vcnt > 16 ? 16 : vcnt;

        // --- stage edge metadata (lanes 0..15, zero-pad invalid) ---
        if (lane < 16) {
            int i = lane;
            if (i < vcnt) {
                int e = bucket[(size_t)n * CAP + ch * 16 + i];
                SRC[i] = edge_src[e];
                *(float4*)&EA[i][0] = ((const float4*)edge_attr)[e];
                *(float4*)&ES[i][0] = ((const float4*)edge_scalars)[2 * e];
                *(float4*)&ES[i][4] = ((const float4*)edge_scalars)[2 * e + 1];
            } else {
                float4 z = make_float4(0.f, 0.f, 0.f, 0.f);
                SRC[i] = 0;
                *(float4*)&EA[i][0] = z;
                *(float4*)&ES[i][0] = z;
                *(float4*)&ES[i][4] = z;
            }
        }
        __syncthreads();

        // --- issue ALL f-gathers into registers (overlap with MLP below) ---
        float gs[16], g0[16], g1[16], g2[16];
        #pragma unroll
        for (int i = 0; i < 16; ++i) {
            const float* fs = f + (size_t)SRC[i] * 160;
            gs[i] = fs[lane];
            g0[i] = fs[wv3 + 0];
            g1[i] = fs[wv3 + 1];
            g2[i] = fs[wv3 + 2];
        }

        // --- H fill ---
        #pragma unroll 4
        for (int i = 0; i < 16; ++i) {
            float4 e0 = *(const float4*)&ES[i][0];
            float4 e1 = *(const float4*)&ES[i][4];
            float acc = e0.x * fw1[0] + e0.y * fw1[1] + e0.z * fw1[2] + e0.w * fw1[3]
                      + e1.x * fw1[4] + e1.y * fw1[5] + e1.z * fw1[6] + e1.w * fw1[7];
            acc *= RS8;
            Hl[i * 64 + lane] = (_Float16)(acc / (1.f + __expf(-acc)));
        }
        __syncthreads();

        // --- W(16x192) = H @ fc_w2' via MFMA (B frags from global, L1-hot) ---
        v8h A0 = *(const v8h*)&Hl[m16 * 64 + quad * 8];
        v8h A1 = *(const v8h*)&Hl[m16 * 64 + 32 + quad * 8];
        #pragma unroll
        for (int t = 0; t < 12; ++t) {
            v8h B0 = *(const v8h*)&Bw2[(0 * 12 + t) * 512 + lane * 8];
            v8h B1 = *(const v8h*)&Bw2[(1 * 12 + t) * 512 + lane * 8];
            f32x4 c = {0.f, 0.f, 0.f, 0.f};
            c = MFMA16(A0, B0, c);
            c = MFMA16(A1, B1, c);
            #pragma unroll
            for (int r = 0; r < 4; ++r)
                Wl[(quad * 4 + r) * 208 + t * 16 + m16] = (_Float16)c[r];
        }
        __syncthreads();

        // --- TP: branch-free over all 16 (padded edges contribute 0) ---
        #pragma unroll 4
        for (int i = 0; i < 16; ++i) {
            float W0 = (float)Wl[i * 208 + lane];
            float W1 = (float)Wl[i * 208 + 64 + lane];
            float W2 = (float)Wl[i * 208 + 128 + lane];
            float4 ea = *(const float4*)&EA[i][0];
            a0 += gs[i] * ea.x * W0;                                    // m0a
            float gW1 = gs[i] * W1;
            a1x += gW1 * ea.y; a1y += gW1 * ea.z; a1z += gW1 * ea.w;    // m1a
            if (lane < 32) {
                float t2 = ea.x * W2;
                a2x += g0[i] * t2; a2y += g1[i] * t2; a2z += g2[i] * t2; // m1b
            } else {
                a2x += (g0[i] * ea.y + g1[i] * ea.z + g2[i] * ea.w)
                       * (INV3 * W2);                                    // m0b
            }
        }
        __syncthreads();
    }

    // --- store mid (f16, raw sums; rs folded into epilogue weights) ---
    _Float16* md = mid16 + (size_t)n * 384;
    md[lane] = (_Float16)a0;
    md[96 + lane * 3 + 0] = (_Float16)a1x;
    md[96 + lane * 3 + 1] = (_Float16)a1y;
    md[96 + lane * 3 + 2] = (_Float16)a1z;
    if (lane < 32) {
        md[288 + wv * 3 + 0] = (_Float16)a2x;
        md[288 + wv * 3 + 1] = (_Float16)a2y;
        md[288 + wv * 3 + 2] = (_Float16)a2z;
    } else {
        md[64 + wv] = (_Float16)a2x;
    }
}

// ---------------------------------------------------------------------------
// Final: batched MFMA epilogue, 16 nodes per single-wave block.
// out = cos(angle)*scfeat + sin(angle)*conv ; rs folded into lin2 B-scales.
// ---------------------------------------------------------------------------
__global__ __launch_bounds__(64) void final_mfma(
    const float* __restrict__ ni, const float* __restrict__ na,
    const _Float16* __restrict__ mid16, const _Float16* __restrict__ Bsw,
    const float* __restrict__ lin3_w, const int* __restrict__ nn,
    float* __restrict__ out, int N)
{
    __shared__ __align__(16) _Float16 Ms[16][104];
    __shared__ __align__(16) _Float16 Mv[3][16][104];
    __shared__ __align__(16) _Float16 Xs[16][72];
    __shared__ __align__(16) _Float16 Xv[3][16][40];
    __shared__ float At[16], CA[16], SA[16];
    const int lane = threadIdx.x;
    const int n0 = blockIdx.x * 16;

    // --- stage mid: j -> Ms (j<96) else Mv[(j-96)%3][.][(j-96)/3] ---
    _Float16* mdst[6];
    #pragma unroll
    for (int t = 0; t < 6; ++t) {
        int j = lane + t * 64;
        mdst[t] = (j < 96) ? &Ms[0][j] : &Mv[(j - 96) % 3][0][(j - 96) / 3];
    }
    for (int m = 0; m < 16; ++m) {
        const _Float16* row = mid16 + (size_t)min(n0 + m, N - 1) * 384;
        #pragma unroll
        for (int t = 0; t < 6; ++t) mdst[t][m * 104] = row[lane + t * 64];
    }
    // --- stage node_input (like prep) ---
    const int j1 = lane + 64, j2 = lane + 128;
    _Float16* xd1 = &Xv[(j1 - 64) % 3][0][(j1 - 64) / 3];
    _Float16* xd2 = (lane < 32) ? &Xv[(j2 - 64) % 3][0][(j2 - 64) / 3] : (_Float16*)0;
    for (int m = 0; m < 16; ++m) {
        const float* row = ni + (size_t)min(n0 + m, N - 1) * 160;
        Xs[m][lane] = (_Float16)row[lane];
        xd1[m * 40] = (_Float16)row[j1];
        if (lane < 32) xd2[m * 40] = (_Float16)row[j2];
    }
    if (lane < 16) At[lane] = na[min(n0 + lane, N - 1)];
    __syncthreads();

    // --- angle per node (lanes 0..15) ---
    if (lane < 16) {
        float rs = rsqrtf((float)nn[0]);
        float ang = 0.f;
        #pragma unroll 8
        for (int k = 0; k < 96; ++k) ang += (float)Ms[lane][k] * lin3_w[k];
        ang *= 0.1f * RS96 * rs * At[lane];
        CA[lane] = cosf(ang);
        SA[lane] = sinf(ang);
    }
    __syncthreads();

    const int m16 = lane & 15, quad = lane >> 4;
    v8h As[3], Ax0, Ax1;
    #pragma unroll
    for (int ks = 0; ks < 3; ++ks) As[ks] = *(const v8h*)&Ms[m16][ks * 32 + quad * 8];
    Ax0 = *(const v8h*)&Xs[m16][quad * 8];
    Ax1 = *(const v8h*)&Xs[m16][32 + quad * 8];

    const _Float16* Bl2w0 = Bsw + OFF_L2W0;
    const _Float16* Bscw0 = Bsw + OFF_SCW0;
    #pragma unroll
    for (int nt = 0; nt < 4; ++nt) {
        f32x4 c = {0.f, 0.f, 0.f, 0.f};
        #pragma unroll
        for (int ks = 0; ks < 3; ++ks)
            c = MFMA16(As[ks], *(const v8h*)&Bl2w0[(ks * 4 + nt) * 512 + lane * 8], c);
        f32x4 s = {0.f, 0.f, 0.f, 0.f};
        s = MFMA16(Ax0, *(const v8h*)&Bscw0[(0 * 4 + nt) * 512 + lane * 8], s);
        s = MFMA16(Ax1, *(const v8h*)&Bscw0[(1 * 4 + nt) * 512 + lane * 8], s);
        #pragma unroll
        for (int r = 0; r < 4; ++r) {
            int rr = quad * 4 + r, n = n0 + rr;
            if (n < N)
                out[(size_t)n * 160 + nt * 16 + m16] =
                    At[rr] * (CA[rr] * s[r] + SA[rr] * c[r]);
        }
    }
    const _Float16* Bl2w1 = Bsw + OFF_L2W1;
    const _Float16* Bscw1 = Bsw + OFF_SCW1;
    #pragma unroll
    for (int d = 0; d < 3; ++d) {
        v8h Am0 = *(const v8h*)&Mv[d][m16][0 * 32 + quad * 8];
        v8h Am1 = *(const v8h*)&Mv[d][m16][1 * 32 + quad * 8];
        v8h Am2 = *(const v8h*)&Mv[d][m16][2 * 32 + quad * 8];
        v8h Axv = *(const v8h*)&Xv[d][m16][quad * 8];
        #pragma unroll
        for (int nt = 0; nt < 2; ++nt) {
            f32x4 c = {0.f, 0.f, 0.f, 0.f};
            c = MFMA16(Am0, *(const v8h*)&Bl2w1[(0 * 2 + nt) * 512 + lane * 8], c);
            c = MFMA16(Am1, *(const v8h*)&Bl2w1[(1 * 2 + nt) * 512 + lane * 8], c);
            c = MFMA16(Am2, *(const v8h*)&Bl2w1[(2 * 2 + nt) * 512 + lane * 8], c);
            f32x4 s = {0.f, 0.f, 0.f, 0.f};
            s = MFMA16(Axv, *(const v8h*)&Bscw1[nt * 512 + lane * 8], s);
            #pragma unroll
            for (int r = 0; r < 4; ++r) {
                int rr = quad * 4 + r, n = n0 + rr;
                if (n < N)
                    out[(size_t)n * 160 + 64 + (nt * 16 + m16) * 3 + d] =
                        At[rr] * (CA[rr] * s[r] + SA[rr] * c[r]);
            }
        }
    }
}

// ---------------------------------------------------------------------------
extern "C" void kernel_launch(void* const* d_in, const int* in_sizes, int n_in,
                              void* d_out, int out_size, void* d_ws, size_t ws_size,
                              hipStream_t stream) {
    const float* node_input   = (const float*)d_in[0];
    const float* node_attr    = (const float*)d_in[1];
    const float* edge_attr    = (const float*)d_in[2];
    const float* edge_scalars = (const float*)d_in[3];
    const float* sc_w0        = (const float*)d_in[4];
    const float* sc_w1        = (const float*)d_in[5];
    const float* lin1_w0      = (const float*)d_in[6];
    const float* lin1_w1      = (const float*)d_in[7];
    const float* fc_w1        = (const float*)d_in[8];
    const float* fc_w2        = (const float*)d_in[9];
    const float* lin2_w0      = (const float*)d_in[10];
    const float* lin2_w1      = (const float*)d_in[11];
    const float* lin3_w       = (const float*)d_in[12];
    const int*   edge_src     = (const int*)d_in[13];
    const int*   edge_dst     = (const int*)d_in[14];
    const int*   num_neigh    = (const int*)d_in[15];

    int N = in_sizes[0] / 160;
    int E = in_sizes[13];

    // workspace layout
    char* ws = (char*)d_ws;
    size_t off = 0;
    float* f = (float*)(ws + off);            off += ((size_t)N * 160 * 4 + 255) & ~(size_t)255;
    int* deg = (int*)(ws + off);              off += ((size_t)N * 4 + 255) & ~(size_t)255;
    int* bucket = (int*)(ws + off);           off += ((size_t)N * CAP * 4 + 255) & ~(size_t)255;
    _Float16* mid16 = (_Float16*)(ws + off);  off += ((size_t)N * 384 * 2 + 255) & ~(size_t)255;
    _Float16* Bsw = (_Float16*)(ws + off);    off += (SWZ_TOTAL * 2 + 255) & ~(size_t)255;

    hipMemsetAsync(deg, 0, (size_t)N * sizeof(int), stream);

    fill_csr<<<(E + 255) / 256, 256, 0, stream>>>(edge_dst, deg, bucket, E);
    swizzle_all<<<(SWZ_TOTAL + 255) / 256, 256, 0, stream>>>(
        fc_w2, lin2_w0, lin2_w1, sc_w0, sc_w1, lin1_w0, lin1_w1, num_neigh, Bsw);
    prep_mfma<<<(N + 15) / 16, 64, 0, stream>>>(node_input, node_attr, Bsw, f, N);

    node_main<<<N, 64, 0, stream>>>(edge_attr, edge_scalars, fc_w1, f, Bsw,
                                    deg, bucket, edge_src, mid16, N);

    final_mfma<<<(N + 15) / 16, 64, 0, stream>>>(node_input, node_attr, mid16, Bsw,
                                                 lin3_w, num_neigh, (float*)d_out, N);
}

// Round 5
// 643.141 us; speedup vs baseline: 1.3607x; 1.3607x over previous
//
#include <hip/hip_runtime.h>
#include <math.h>

#define INV3 0.57735026918962576f       // 1/sqrt(3)
#define RS8  0.35355339059327373f       // 1/sqrt(8)
#define RS32 0.17677669529663687f       // 1/sqrt(32)
#define RS64 0.125f                     // 1/sqrt(64)
#define RS96 0.10206207261596575f       // 1/sqrt(96)
#define CAP  64                          // max in-degree (Poisson(16): P(>64) ~ 1e-20)

typedef _Float16 v8h   __attribute__((ext_vector_type(8)));
typedef float    f32x4 __attribute__((ext_vector_type(4)));
typedef unsigned int u32;

// swizzled-weight arena offsets (in f16 elements)
#define OFF_W2    0        // fc_w2   64x192, *RS64       : 2ks x 12nt
#define OFF_L2W0  12288    // lin2_w0 96x64,  *RS96*rs    : 3ks x 4nt
#define OFF_L2W1  18432    // lin2_w1 96x32,  *RS96*rs    : 3ks x 2nt
#define OFF_SCW0  21504    // sc_w0   64x64,  *RS64       : 2ks x 4nt
#define OFF_SCW1  25600    // sc_w1   32x32,  *RS32       : 1ks x 2nt
#define OFF_L1W0  26624    // lin1_w0 64x64,  *RS64       : 2ks x 4nt
#define OFF_L1W1  30720    // lin1_w1 32x32,  *RS32       : 1ks x 2nt
#define SWZ_TOTAL 31744

#define MFMA16(a,b,c) __builtin_amdgcn_mfma_f32_16x16x32_f16((a),(b),(c),0,0,0)

// async global->LDS, 4 B/lane; g and l are per-lane (contiguous in lane order)
__device__ __forceinline__ void gl_lds4(const void* g, void* l) {
    __builtin_amdgcn_global_load_lds(
        (const __attribute__((address_space(1))) u32*)g,
        (__attribute__((address_space(3))) u32*)l, 4, 0, 0);
}

// ---------------------------------------------------------------------------
// Swizzle all weight matrices into MFMA B-fragment f16 arena.
// ---------------------------------------------------------------------------
__global__ void swizzle_all(const float* __restrict__ fc_w2,
                            const float* __restrict__ lin2_w0,
                            const float* __restrict__ lin2_w1,
                            const float* __restrict__ sc_w0,
                            const float* __restrict__ sc_w1,
                            const float* __restrict__ lin1_w0,
                            const float* __restrict__ lin1_w1,
                            const int* __restrict__ nn,
                            _Float16* __restrict__ B) {
    int idx = blockIdx.x * blockDim.x + threadIdx.x;
    if (idx >= SWZ_TOTAL) return;
    float rs = rsqrtf((float)nn[0]);
    const float* W; int M, off; float s;
    if      (idx < OFF_L2W0) { W = fc_w2;   M = 192; off = OFF_W2;   s = RS64; }
    else if (idx < OFF_L2W1) { W = lin2_w0; M = 64;  off = OFF_L2W0; s = RS96 * rs; }
    else if (idx < OFF_SCW0) { W = lin2_w1; M = 32;  off = OFF_L2W1; s = RS96 * rs; }
    else if (idx < OFF_SCW1) { W = sc_w0;   M = 64;  off = OFF_SCW0; s = RS64; }
    else if (idx < OFF_L1W0) { W = sc_w1;   M = 32;  off = OFF_SCW1; s = RS32; }
    else if (idx < OFF_L1W1) { W = lin1_w0; M = 64;  off = OFF_L1W0; s = RS64; }
    else                     { W = lin1_w1; M = 32;  off = OFF_L1W1; s = RS32; }
    int rel  = idx - off;
    int j    = rel & 7, l = (rel >> 3) & 63, frag = rel >> 9;
    int NT   = M >> 4;
    int nt   = frag % NT, ks = frag / NT;
    int k    = ks * 32 + ((l >> 4) << 3) + j;
    int n    = (nt << 4) + (l & 15);
    B[idx] = (_Float16)(W[k * M + n] * s);
}

// ---------------------------------------------------------------------------
// CSR build
// ---------------------------------------------------------------------------
__global__ void fill_csr(const int* __restrict__ edge_dst, int* __restrict__ deg,
                         int* __restrict__ bucket, int E) {
    int e = blockIdx.x * blockDim.x + threadIdx.x;
    if (e >= E) return;
    int d = edge_dst[e];
    int pos = atomicAdd(&deg[d], 1);
    if (pos < CAP) bucket[(size_t)d * CAP + pos] = e;
}

// ---------------------------------------------------------------------------
// Prep: f(f16) = lin1-fctp(node_input) via MFMA, 16 nodes per wave.
// ---------------------------------------------------------------------------
__global__ __launch_bounds__(64) void prep_mfma(
    const float* __restrict__ ni, const float* __restrict__ na,
    const _Float16* __restrict__ Bsw, _Float16* __restrict__ fout, int N)
{
    __shared__ __align__(16) _Float16 Xs[16][72];
    __shared__ __align__(16) _Float16 Xv[3][16][40];
    __shared__ float At[16];
    const int lane = threadIdx.x;
    const int n0 = blockIdx.x * 16;
    const int j1 = lane + 64, j2 = lane + 128;
    _Float16* xd1 = &Xv[(j1 - 64) % 3][0][(j1 - 64) / 3];
    _Float16* xd2 = (lane < 32) ? &Xv[(j2 - 64) % 3][0][(j2 - 64) / 3] : (_Float16*)0;
    for (int m = 0; m < 16; ++m) {
        const float* row = ni + (size_t)min(n0 + m, N - 1) * 160;
        Xs[m][lane] = (_Float16)row[lane];
        xd1[m * 40] = (_Float16)row[j1];
        if (lane < 32) xd2[m * 40] = (_Float16)row[j2];
    }
    if (lane < 16) At[lane] = na[min(n0 + lane, N - 1)];
    __syncthreads();

    const int m16 = lane & 15, quad = lane >> 4;
    v8h A0 = *(const v8h*)&Xs[m16][quad * 8];
    v8h A1 = *(const v8h*)&Xs[m16][32 + quad * 8];
    const _Float16* B0 = Bsw + OFF_L1W0;
    #pragma unroll
    for (int nt = 0; nt < 4; ++nt) {
        f32x4 c = {0.f, 0.f, 0.f, 0.f};
        c = MFMA16(A0, *(const v8h*)&B0[(0 * 4 + nt) * 512 + lane * 8], c);
        c = MFMA16(A1, *(const v8h*)&B0[(1 * 4 + nt) * 512 + lane * 8], c);
        #pragma unroll
        for (int r = 0; r < 4; ++r) {
            int rr = quad * 4 + r, n = n0 + rr;
            if (n < N) fout[(size_t)n * 160 + nt * 16 + m16] = (_Float16)(c[r] * At[rr]);
        }
    }
    const _Float16* B1 = Bsw + OFF_L1W1;
    #pragma unroll
    for (int d = 0; d < 3; ++d) {
        v8h Ad = *(const v8h*)&Xv[d][m16][quad * 8];
        #pragma unroll
        for (int nt = 0; nt < 2; ++nt) {
            f32x4 c = {0.f, 0.f, 0.f, 0.f};
            c = MFMA16(Ad, *(const v8h*)&B1[nt * 512 + lane * 8], c);
            #pragma unroll
            for (int r = 0; r < 4; ++r) {
                int rr = quad * 4 + r, n = n0 + rr;
                if (n < N)
                    fout[(size_t)n * 160 + 64 + (nt * 16 + m16) * 3 + d] =
                        (_Float16)(c[r] * At[rr]);
            }
        }
    }
}

// ---------------------------------------------------------------------------
// Aggregation: one node per single-wave block.
// All edge meta prefetched (1 edge/lane). Per chunk: issue f-gather DMAs
// (global_load_lds -> Ft), H-fill (shfl-broadcast es), 24 MFMA -> Wl, TP.
// mid16 written in PLANAR layout: [0..95]=scalars, then 3 planes of 96.
// ---------------------------------------------------------------------------
__global__ __launch_bounds__(64, 3) void node_main(
    const float* __restrict__ edge_attr,     // E x 4
    const float* __restrict__ edge_scalars,  // E x 8
    const float* __restrict__ fc_w1,         // 8 x 64
    const _Float16* __restrict__ fh,         // N x 160 (f16, padded alloc)
    const _Float16* __restrict__ Bsw,        // swizzled arena
    const int* __restrict__ deg,
    const int* __restrict__ bucket,
    const int* __restrict__ edge_src,
    _Float16* __restrict__ mid16,            // N x 384 planar
    int N)
{
    __shared__ __align__(16) _Float16 Ft[16][256];   // 8192 B (gathered f rows)
    __shared__ __align__(16) _Float16 U[16 * 208];   // 6656 B (Hl aliases front)
    _Float16* Hl = U;

    const int lane = threadIdx.x;
    const int n    = blockIdx.x;
    if (n >= N) return;

    float fw1[8];
    #pragma unroll
    for (int u = 0; u < 8; ++u) fw1[u] = fc_w1[u * 64 + lane];

    int deg_n = min(deg[n], CAP);
    int nch = (deg_n + 15) >> 4;

    // --- prefetch ALL edge meta: one edge per lane ---
    int e = (lane < deg_n) ? bucket[(size_t)n * CAP + lane] : 0;
    int src = edge_src[e];
    float4 ea4 = ((const float4*)edge_attr)[e];
    float4 es0 = ((const float4*)edge_scalars)[2 * e];
    float4 es1 = ((const float4*)edge_scalars)[2 * e + 1];
    if (lane >= deg_n) {
        float4 z = make_float4(0.f, 0.f, 0.f, 0.f);
        ea4 = z; es0 = z; es1 = z;
    }

    float a0 = 0.f, a1x = 0.f, a1y = 0.f, a1z = 0.f;
    float a2x = 0.f, a2y = 0.f, a2z = 0.f;
    const int m16  = lane & 15;
    const int quad = lane >> 4;
    const int wv   = lane & 31;
    const _Float16* Bw2 = Bsw + OFF_W2;

    for (int ch = 0; ch < nch; ++ch) {
        // --- issue all gather DMAs for this chunk (async into Ft) ---
        #pragma unroll
        for (int i = 0; i < 16; ++i) {
            int srci = __shfl(src, ch * 16 + i);
            const char* g = (const char*)(fh + (size_t)srci * 160);
            char* l = (char*)&Ft[i][0];
            gl_lds4(g + lane * 4, l + lane * 4);
            gl_lds4(g + 256 + lane * 4, l + 256 + lane * 4);  // pad over-read, harmless
        }

        __syncthreads();   // prev chunk's Wl reads done before Hl overwrite

        // --- H fill: broadcast es via shfl (uniform index -> readlane) ---
        #pragma unroll 4
        for (int i = 0; i < 16; ++i) {
            int el = ch * 16 + i;
            float acc = __shfl(es0.x, el) * fw1[0] + __shfl(es0.y, el) * fw1[1]
                      + __shfl(es0.z, el) * fw1[2] + __shfl(es0.w, el) * fw1[3]
                      + __shfl(es1.x, el) * fw1[4] + __shfl(es1.y, el) * fw1[5]
                      + __shfl(es1.z, el) * fw1[6] + __shfl(es1.w, el) * fw1[7];
            acc *= RS8;
            Hl[i * 64 + lane] = (_Float16)(acc / (1.f + __expf(-acc)));
        }
        __syncthreads();

        // --- W(16x192) = H @ fc_w2' via MFMA (B frags L1-hot from global) ---
        v8h A0 = *(const v8h*)&Hl[m16 * 64 + quad * 8];
        v8h A1 = *(const v8h*)&Hl[m16 * 64 + 32 + quad * 8];
        __syncthreads();   // A-frag reads complete before Wl overwrites Hl region
        #pragma unroll
        for (int t = 0; t < 12; ++t) {
            v8h B0 = *(const v8h*)&Bw2[(0 * 12 + t) * 512 + lane * 8];
            v8h B1 = *(const v8h*)&Bw2[(1 * 12 + t) * 512 + lane * 8];
            f32x4 c = {0.f, 0.f, 0.f, 0.f};
            c = MFMA16(A0, B0, c);
            c = MFMA16(A1, B1, c);
            #pragma unroll
            for (int r = 0; r < 4; ++r)
                U[(quad * 4 + r) * 208 + t * 16 + m16] = (_Float16)c[r];
        }

        __builtin_amdgcn_s_waitcnt(0);   // DMA (vmcnt) + LDS writes drained
        __syncthreads();

        // --- TP over 16 edges (padded edges have W=0, ea=0 -> contribute 0) ---
        #pragma unroll 4
        for (int i = 0; i < 16; ++i) {
            int el = ch * 16 + i;
            float eax = __shfl(ea4.x, el);
            float eay = __shfl(ea4.y, el);
            float eaz = __shfl(ea4.z, el);
            float eaw = __shfl(ea4.w, el);
            float W0 = (float)U[i * 208 + lane];
            float W1 = (float)U[i * 208 + 64 + lane];
            float W2 = (float)U[i * 208 + 128 + lane];
            float gs = (float)Ft[i][lane];
            float g0 = (float)Ft[i][64 + wv * 3 + 0];
            float g1 = (float)Ft[i][64 + wv * 3 + 1];
            float g2 = (float)Ft[i][64 + wv * 3 + 2];
            a0 += gs * eax * W0;                                   // m0a
            float gW1 = gs * W1;
            a1x += gW1 * eay; a1y += gW1 * eaz; a1z += gW1 * eaw;  // m1a
            if (lane < 32) {
                float t2 = eax * W2;
                a2x += g0 * t2; a2y += g1 * t2; a2z += g2 * t2;    // m1b
            } else {
                a2x += (g0 * eay + g1 * eaz + g2 * eaw) * (INV3 * W2);  // m0b
            }
        }
        __syncthreads();
    }

    // --- store mid (f16, raw sums, PLANAR layout) ---
    _Float16* md = mid16 + (size_t)n * 384;
    md[lane] = (_Float16)a0;                       // scalars: m0a
    md[96 + 0 * 96 + lane] = (_Float16)a1x;        // plane d: [lane]=m1a_d
    md[96 + 1 * 96 + lane] = (_Float16)a1y;
    md[96 + 2 * 96 + lane] = (_Float16)a1z;
    if (lane < 32) {
        md[96 + 0 * 96 + 64 + wv] = (_Float16)a2x; // [64+wv]=m1b_d
        md[96 + 1 * 96 + 64 + wv] = (_Float16)a2y;
        md[96 + 2 * 96 + 64 + wv] = (_Float16)a2z;
    } else {
        md[64 + wv] = (_Float16)a2x;               // scalars: m0b
    }
}

// ---------------------------------------------------------------------------
// Final: batched MFMA epilogue, 16 nodes per wave. mid16 is planar ->
// staging via int-pair loads (pairs never straddle the 96-element regions).
// ---------------------------------------------------------------------------
__global__ __launch_bounds__(64) void final_mfma(
    const float* __restrict__ ni, const float* __restrict__ na,
    const _Float16* __restrict__ mid16, const _Float16* __restrict__ Bsw,
    const float* __restrict__ lin3_w, const int* __restrict__ nn,
    float* __restrict__ out, int N)
{
    __shared__ __align__(16) _Float16 Mall[4][16][104];  // [0]=Ms, [1+d]=Mv[d]
    __shared__ __align__(16) _Float16 Xs[16][72];
    __shared__ __align__(16) _Float16 Xv[3][16][40];
    __shared__ float At[16], CA[16], SA[16];
    const int lane = threadIdx.x;
    const int n0 = blockIdx.x * 16;

    // --- stage mid (planar): 3 int loads per row per lane ---
    _Float16* mdst[3];
    #pragma unroll
    for (int t = 0; t < 3; ++t) {
        int p = 2 * lane + t * 128;
        int r = (p < 96) ? 0 : 1 + (p - 96) / 96;
        int u = (p < 96) ? p : (p - 96) % 96;
        mdst[t] = &Mall[r][0][u];
    }
    for (int m = 0; m < 16; ++m) {
        const int* row32 = (const int*)(mid16 + (size_t)min(n0 + m, N - 1) * 384);
        #pragma unroll
        for (int t = 0; t < 3; ++t)
            *(int*)&mdst[t][m * 104] = row32[lane + t * 64];
    }
    // --- stage node_input ---
    const int j1 = lane + 64, j2 = lane + 128;
    _Float16* xd1 = &Xv[(j1 - 64) % 3][0][(j1 - 64) / 3];
    _Float16* xd2 = (lane < 32) ? &Xv[(j2 - 64) % 3][0][(j2 - 64) / 3] : (_Float16*)0;
    for (int m = 0; m < 16; ++m) {
        const float* row = ni + (size_t)min(n0 + m, N - 1) * 160;
        Xs[m][lane] = (_Float16)row[lane];
        xd1[m * 40] = (_Float16)row[j1];
        if (lane < 32) xd2[m * 40] = (_Float16)row[j2];
    }
    if (lane < 16) At[lane] = na[min(n0 + lane, N - 1)];
    __syncthreads();

    if (lane < 16) {
        float rs = rsqrtf((float)nn[0]);
        float ang = 0.f;
        #pragma unroll 8
        for (int k = 0; k < 96; ++k) ang += (float)Mall[0][lane][k] * lin3_w[k];
        ang *= 0.1f * RS96 * rs * At[lane];
        CA[lane] = cosf(ang);
        SA[lane] = sinf(ang);
    }
    __syncthreads();

    const int m16 = lane & 15, quad = lane >> 4;
    v8h As[3], Ax0, Ax1;
    #pragma unroll
    for (int ks = 0; ks < 3; ++ks) As[ks] = *(const v8h*)&Mall[0][m16][ks * 32 + quad * 8];
    Ax0 = *(const v8h*)&Xs[m16][quad * 8];
    Ax1 = *(const v8h*)&Xs[m16][32 + quad * 8];

    const _Float16* Bl2w0 = Bsw + OFF_L2W0;
    const _Float16* Bscw0 = Bsw + OFF_SCW0;
    #pragma unroll
    for (int nt = 0; nt < 4; ++nt) {
        f32x4 c = {0.f, 0.f, 0.f, 0.f};
        #pragma unroll
        for (int ks = 0; ks < 3; ++ks)
            c = MFMA16(As[ks], *(const v8h*)&Bl2w0[(ks * 4 + nt) * 512 + lane * 8], c);
        f32x4 s = {0.f, 0.f, 0.f, 0.f};
        s = MFMA16(Ax0, *(const v8h*)&Bscw0[(0 * 4 + nt) * 512 + lane * 8], s);
        s = MFMA16(Ax1, *(const v8h*)&Bscw0[(1 * 4 + nt) * 512 + lane * 8], s);
        #pragma unroll
        for (int r = 0; r < 4; ++r) {
            int rr = quad * 4 + r, n = n0 + rr;
            if (n < N)
                out[(size_t)n * 160 + nt * 16 + m16] =
                    At[rr] * (CA[rr] * s[r] + SA[rr] * c[r]);
        }
    }
    const _Float16* Bl2w1 = Bsw + OFF_L2W1;
    const _Float16* Bscw1 = Bsw + OFF_SCW1;
    #pragma unroll
    for (int d = 0; d < 3; ++d) {
        v8h Am0 = *(const v8h*)&Mall[1 + d][m16][0 * 32 + quad * 8];
        v8h Am1 = *(const v8h*)&Mall[1 + d][m16][1 * 32 + quad * 8];
        v8h Am2 = *(const v8h*)&Mall[1 + d][m16][2 * 32 + quad * 8];
        v8h Axv = *(const v8h*)&Xv[d][m16][quad * 8];
        #pragma unroll
        for (int nt = 0; nt < 2; ++nt) {
            f32x4 c = {0.f, 0.f, 0.f, 0.f};
            c = MFMA16(Am0, *(const v8h*)&Bl2w1[(0 * 2 + nt) * 512 + lane * 8], c);
            c = MFMA16(Am1, *(const v8h*)&Bl2w1[(1 * 2 + nt) * 512 + lane * 8], c);
            c = MFMA16(Am2, *(const v8h*)&Bl2w1[(2 * 2 + nt) * 512 + lane * 8], c);
            f32x4 s = {0.f, 0.f, 0.f, 0.f};
            s = MFMA16(Axv, *(const v8h*)&Bscw1[nt * 512 + lane * 8], s);
            #pragma unroll
            for (int r = 0; r < 4; ++r) {
                int rr = quad * 4 + r, n = n0 + rr;
                if (n < N)
                    out[(size_t)n * 160 + 64 + (nt * 16 + m16) * 3 + d] =
                        At[rr] * (CA[rr] * s[r] + SA[rr] * c[r]);
            }
        }
    }
}

// ---------------------------------------------------------------------------
extern "C" void kernel_launch(void* const* d_in, const int* in_sizes, int n_in,
                              void* d_out, int out_size, void* d_ws, size_t ws_size,
                              hipStream_t stream) {
    const float* node_input   = (const float*)d_in[0];
    const float* node_attr    = (const float*)d_in[1];
    const float* edge_attr    = (const float*)d_in[2];
    const float* edge_scalars = (const float*)d_in[3];
    const float* sc_w0        = (const float*)d_in[4];
    const float* sc_w1        = (const float*)d_in[5];
    const float* lin1_w0      = (const float*)d_in[6];
    const float* lin1_w1      = (const float*)d_in[7];
    const float* fc_w1        = (const float*)d_in[8];
    const float* fc_w2        = (const float*)d_in[9];
    const float* lin2_w0      = (const float*)d_in[10];
    const float* lin2_w1      = (const float*)d_in[11];
    const float* lin3_w       = (const float*)d_in[12];
    const int*   edge_src     = (const int*)d_in[13];
    const int*   edge_dst     = (const int*)d_in[14];
    const int*   num_neigh    = (const int*)d_in[15];

    int N = in_sizes[0] / 160;
    int E = in_sizes[13];

    // workspace layout
    char* ws = (char*)d_ws;
    size_t off = 0;
    _Float16* fh = (_Float16*)(ws + off);     off += ((size_t)N * 160 * 2 + 512 + 255) & ~(size_t)255; // +pad for DMA over-read
    int* deg = (int*)(ws + off);              off += ((size_t)N * 4 + 255) & ~(size_t)255;
    int* bucket = (int*)(ws + off);           off += ((size_t)N * CAP * 4 + 255) & ~(size_t)255;
    _Float16* mid16 = (_Float16*)(ws + off);  off += ((size_t)N * 384 * 2 + 255) & ~(size_t)255;
    _Float16* Bsw = (_Float16*)(ws + off);    off += (SWZ_TOTAL * 2 + 255) & ~(size_t)255;

    hipMemsetAsync(deg, 0, (size_t)N * sizeof(int), stream);

    fill_csr<<<(E + 255) / 256, 256, 0, stream>>>(edge_dst, deg, bucket, E);
    swizzle_all<<<(SWZ_TOTAL + 255) / 256, 256, 0, stream>>>(
        fc_w2, lin2_w0, lin2_w1, sc_w0, sc_w1, lin1_w0, lin1_w1, num_neigh, Bsw);
    prep_mfma<<<(N + 15) / 16, 64, 0, stream>>>(node_input, node_attr, Bsw, fh, N);

    node_main<<<N, 64, 0, stream>>>(edge_attr, edge_scalars, fc_w1, fh, Bsw,
                                    deg, bucket, edge_src, mid16, N);

    final_mfma<<<(N + 15) / 16, 64, 0, stream>>>(node_input, node_attr, mid16, Bsw,
                                                 lin3_w, num_neigh, (float*)d_out, N);
}